// Round 2
// baseline (199.347 us; speedup 1.0000x reference)
//
#include <hip/hip_runtime.h>
#include <hip/hip_bf16.h>

typedef __attribute__((ext_vector_type(4))) float f32x4;
typedef __attribute__((ext_vector_type(8))) short s16x8;

#define DEVI __device__ __forceinline__

constexpr int S = 512, C = 862, P = 96, H = 128, BATCH = 64;
constexpr int CT = 14;  // ceil(862/64)

DEVI short f2bf(float f) {
  unsigned u = __builtin_bit_cast(unsigned, f);
  u += 0x7fffu + ((u >> 16) & 1u);
  return (short)(u >> 16);
}

DEVI unsigned pk2(float a, float b) {
  return (unsigned)(unsigned short)f2bf(a) | ((unsigned)(unsigned short)f2bf(b) << 16);
}

DEVI s16x8 mk8(const float* v) {
  s16x8 r;
#pragma unroll
  for (int i = 0; i < 8; ++i) r[i] = f2bf(v[i]);
  return r;
}

// ---------------- k0: weight conversions ----------------
__global__ __launch_bounds__(256) void k0_convert(
    const float* __restrict__ W1, const float* __restrict__ Wp,
    const float* __restrict__ W2, const float* __restrict__ mem,
    short* __restrict__ W1b, short* __restrict__ Wpb, short* __restrict__ W2b,
    short* __restrict__ memb, short* __restrict__ memTb) {
  int i = blockIdx.x * 256 + threadIdx.x;
  if (i < 65536) { W1b[i] = f2bf(W1[i]); return; }
  i -= 65536;
  if (i < 16384) { Wpb[i] = f2bf(Wp[i]); return; }
  i -= 16384;
  if (i < 24576) { W2b[i] = f2bf(W2[i]); return; }
  i -= 24576;
  if (i < 65536) {
    short v = f2bf(mem[i]);
    memb[i] = v;                              // [f][d]
    memTb[(i & 127) * 512 + (i >> 7)] = v;    // [d][f]
  }
}

// ---------------- k1: r1 = sigmoid(x^T W1^T + b1) ----------------
// grid (14, 64). Double-buffered LDS, reg-prefetch, 1 barrier per K-step.
__global__ __launch_bounds__(256, 3) void k1_repre(
    const float* __restrict__ x, const short* __restrict__ W1b,
    const float* __restrict__ b1, short* __restrict__ R1b) {
  __shared__ short xt[2][64 * 64];    // [c][s] 2x8KB
  __shared__ short w1t[2][128 * 64];  // [h][s] 2x16KB
  const int b = blockIdx.y;
  const int c0 = blockIdx.x * 64;
  const int tid = threadIdx.x;
  const int l = tid & 63, w = tid >> 6;
  const int l15 = l & 15, l4 = l >> 4;
  const int csub = (w >> 1) * 32, hsub = (w & 1) * 64;

  f32x4 acc[2][4];
#pragma unroll
  for (int ct = 0; ct < 2; ++ct)
#pragma unroll
    for (int ht = 0; ht < 4; ++ht) acc[ct][ht] = (f32x4){0.f, 0.f, 0.f, 0.f};

  const int cme = tid & 63;
  const bool cv = (c0 + cme) < C;
  const float* xsrc0 = x + (size_t)b * S * C + c0 + cme;
  const int hh = tid >> 1, half = tid & 1;

  float xv[2][8];
  s16x8 wv[4];
  // prefetch kt=0
  {
#pragma unroll
    for (int j = 0; j < 2; ++j) {
      int o = w + j * 4;
      const float* src = xsrc0 + (size_t)(o * 8) * C;
#pragma unroll
      for (int i = 0; i < 8; ++i) xv[j][i] = cv ? src[(size_t)i * C] : 0.f;
    }
    const short* wsrc = W1b + hh * 512;
#pragma unroll
    for (int q = 0; q < 4; ++q) wv[q] = *(const s16x8*)&wsrc[(half * 4 + q) * 8];
  }

  for (int kt = 0; kt < 8; ++kt) {
    const int pb = kt & 1;
    // write staged regs -> LDS buffer pb
#pragma unroll
    for (int j = 0; j < 2; ++j) {
      int o = w + j * 4;
      int phys = o ^ (cme & 7);
      *(s16x8*)&xt[pb][cme * 64 + phys * 8] = mk8(xv[j]);
    }
#pragma unroll
    for (int q = 0; q < 4; ++q) {
      int ss = half * 4 + q;
      int phys = ss ^ (hh & 7);
      *(s16x8*)&w1t[pb][hh * 64 + phys * 8] = wv[q];
    }
    __syncthreads();
    // issue next tile's global loads (consumed at next iteration's LDS write)
    if (kt < 7) {
      int kn = kt + 1;
#pragma unroll
      for (int j = 0; j < 2; ++j) {
        int o = w + j * 4;
        const float* src = xsrc0 + (size_t)(kn * 64 + o * 8) * C;
#pragma unroll
        for (int i = 0; i < 8; ++i) xv[j][i] = cv ? src[(size_t)i * C] : 0.f;
      }
      const short* wsrc = W1b + hh * 512 + kn * 64;
#pragma unroll
      for (int q = 0; q < 4; ++q) wv[q] = *(const s16x8*)&wsrc[(half * 4 + q) * 8];
    }
    // fragments + MFMA from buffer pb
    s16x8 af[2][2], bf[4][2];
#pragma unroll
    for (int ct = 0; ct < 2; ++ct)
#pragma unroll
      for (int kc = 0; kc < 2; ++kc) {
        int row = csub + ct * 16 + l15;
        int slot = kc * 4 + l4;
        af[ct][kc] = *(const s16x8*)&xt[pb][row * 64 + (slot ^ (row & 7)) * 8];
      }
#pragma unroll
    for (int ht = 0; ht < 4; ++ht)
#pragma unroll
      for (int kc = 0; kc < 2; ++kc) {
        int row = hsub + ht * 16 + l15;
        int slot = kc * 4 + l4;
        bf[ht][kc] = *(const s16x8*)&w1t[pb][row * 64 + (slot ^ (row & 7)) * 8];
      }
#pragma unroll
    for (int ct = 0; ct < 2; ++ct)
#pragma unroll
      for (int ht = 0; ht < 4; ++ht)
#pragma unroll
        for (int kc = 0; kc < 2; ++kc)
          acc[ct][ht] = __builtin_amdgcn_mfma_f32_16x16x32_bf16(
              af[ct][kc], bf[ht][kc], acc[ct][ht], 0, 0, 0);
  }
  // epilogue: + b1, sigmoid, store bf16
#pragma unroll
  for (int ct = 0; ct < 2; ++ct) {
#pragma unroll
    for (int ht = 0; ht < 4; ++ht) {
      int hcol = hsub + ht * 16 + l15;
      float bias = b1[hcol];
#pragma unroll
      for (int e = 0; e < 4; ++e) {
        int crow = csub + ct * 16 + l4 * 4 + e;
        if (c0 + crow < C) {
          float v = acc[ct][ht][e] + bias;
          float sg = 1.f / (1.f + __expf(-v));
          R1b[((size_t)b * C + c0 + crow) * 128 + hcol] = f2bf(sg);
        }
      }
    }
  }
}

// ---------------- k2: fused projector + codebook attention + predictor ----------------
// grid (14, 64). 64 rows/block, 4 waves. All B-operands read from global (L2-resident).
// LDS only for cross-wave r2 and P. Online softmax over 4 slices of 128.
__global__ __launch_bounds__(256, 4) void k2_fused(
    const short* __restrict__ R1b, const short* __restrict__ Wpb,
    const float* __restrict__ bp, const short* __restrict__ memb,
    const short* __restrict__ memTb, const short* __restrict__ W2b,
    const float* __restrict__ b2, float* __restrict__ out) {
  __shared__ short bufR2[64 * 128];  // r2 bf16, swizzled      (16KB)
  __shared__ short bufP[64 * 128];   // P slice / att-out bf16 (16KB)
  __shared__ float redsc[64];
  __shared__ float redsum[64];

  const int b = blockIdx.y, c0 = blockIdx.x * 64;
  const int valid = (C - c0 < 64) ? (C - c0) : 64;
  const int tid = threadIdx.x, l = tid & 63, w = tid >> 6;
  const int l15 = l & 15, l4 = l >> 4;
  const bool evn = (l15 & 1) == 0;
  const size_t n0 = (size_t)b * C + c0;

  // ---- r2 = r1 @ Wp^T + bp : wave w owns rows [16w, 16w+16) ----
  {
    int rloc = 16 * w + l15;
    int rr = rloc < valid ? rloc : valid - 1;  // clamp: stay in-bounds, sane values
    const short* asrc = R1b + (n0 + rr) * 128;
    s16x8 af[4];
#pragma unroll
    for (int kc = 0; kc < 4; ++kc) af[kc] = *(const s16x8*)&asrc[(kc * 4 + l4) * 8];
#pragma unroll
    for (int gt = 0; gt < 8; ++gt) {
      f32x4 acc = (f32x4){0.f, 0.f, 0.f, 0.f};
#pragma unroll
      for (int kc = 0; kc < 4; ++kc) {
        s16x8 bf = *(const s16x8*)&Wpb[(gt * 16 + l15) * 128 + (kc * 4 + l4) * 8];
        acc = __builtin_amdgcn_mfma_f32_16x16x32_bf16(af[kc], bf, acc, 0, 0, 0);
      }
      int g = gt * 16 + l15;
      float bias = bp[g];
#pragma unroll
      for (int e = 0; e < 4; ++e) {
        float v = acc[e] + bias;
        float pv = __shfl_xor(v, 1);
        if (evn) {
          int row = 16 * w + l4 * 4 + e;
          int slot = g >> 3;
          int phys = (slot & 8) | ((slot & 7) ^ (row & 7));
          *(unsigned*)&bufR2[row * 128 + phys * 8 + (g & 7)] = pk2(v, pv);
        }
      }
    }
  }
  __syncthreads();

  // hoisted logits A-frags (own rows of r2)
  s16x8 ar[4];
#pragma unroll
  for (int kc = 0; kc < 4; ++kc) {
    int row = 16 * w + l15;
    int slot = kc * 4 + l4;
    int phys = (slot & 8) | ((slot & 7) ^ (row & 7));
    ar[kc] = *(const s16x8*)&bufR2[row * 128 + phys * 8];
  }

  float m_run[4], s_run[4];
#pragma unroll
  for (int e = 0; e < 4; ++e) { m_run[e] = -1e30f; s_run[e] = 0.f; }
  f32x4 oacc[4][2];
#pragma unroll
  for (int rt = 0; rt < 4; ++rt)
#pragma unroll
    for (int d = 0; d < 2; ++d) oacc[rt][d] = (f32x4){0.f, 0.f, 0.f, 0.f};

  for (int s = 0; s < 4; ++s) {
    // logits: own 16 rows x 128 f, B-frags straight from L2
    f32x4 lg[8];
#pragma unroll
    for (int ft = 0; ft < 8; ++ft) {
      lg[ft] = (f32x4){0.f, 0.f, 0.f, 0.f};
#pragma unroll
      for (int kc = 0; kc < 4; ++kc) {
        s16x8 bf = *(const s16x8*)&memb[(s * 128 + ft * 16 + l15) * 128 + (kc * 4 + l4) * 8];
        lg[ft] = __builtin_amdgcn_mfma_f32_16x16x32_bf16(ar[kc], bf, lg[ft], 0, 0, 0);
      }
    }
    // online softmax + packed P store
#pragma unroll
    for (int e = 0; e < 4; ++e) {
      float mx = lg[0][e];
#pragma unroll
      for (int ft = 1; ft < 8; ++ft) mx = fmaxf(mx, lg[ft][e]);
      mx = fmaxf(mx, __shfl_xor(mx, 1));
      mx = fmaxf(mx, __shfl_xor(mx, 2));
      mx = fmaxf(mx, __shfl_xor(mx, 4));
      mx = fmaxf(mx, __shfl_xor(mx, 8));
      float mn = fmaxf(m_run[e], mx);
      float sc = __expf(m_run[e] - mn);
      float ps = 0.f;
#pragma unroll
      for (int ft = 0; ft < 8; ++ft) {
        float p = __expf(lg[ft][e] - mn);
        lg[ft][e] = p;
        ps += p;
      }
      ps += __shfl_xor(ps, 1);
      ps += __shfl_xor(ps, 2);
      ps += __shfl_xor(ps, 4);
      ps += __shfl_xor(ps, 8);
      s_run[e] = s_run[e] * sc + ps;
      m_run[e] = mn;
      int row = 16 * w + l4 * 4 + e;
      if (l15 == 0) {
        redsc[row] = sc;
        if (s == 3) redsum[row] = s_run[e];
      }
#pragma unroll
      for (int ft = 0; ft < 8; ++ft) {
        float v = lg[ft][e];
        float pv = __shfl_xor(v, 1);
        if (evn) {
          int fc = ft * 16 + l15;
          int slot = fc >> 3;
          int phys = (slot & 8) | ((slot & 7) ^ (row & 7));
          *(unsigned*)&bufP[row * 128 + phys * 8 + (fc & 7)] = pk2(v, pv);
        }
      }
    }
    __syncthreads();  // (b) P + redsc visible
    // PV: wave w owns d-columns [32w, 32w+32); rescale then accumulate
#pragma unroll
    for (int rt = 0; rt < 4; ++rt)
#pragma unroll
      for (int e = 0; e < 4; ++e) {
        float sc = redsc[rt * 16 + l4 * 4 + e];
        oacc[rt][0][e] *= sc;
        oacc[rt][1][e] *= sc;
      }
#pragma unroll
    for (int rt = 0; rt < 4; ++rt) {
      s16x8 ap[4];
#pragma unroll
      for (int kc = 0; kc < 4; ++kc) {
        int row = rt * 16 + l15;
        int slot = kc * 4 + l4;
        int phys = (slot & 8) | ((slot & 7) ^ (row & 7));
        ap[kc] = *(const s16x8*)&bufP[row * 128 + phys * 8];
      }
#pragma unroll
      for (int dtl = 0; dtl < 2; ++dtl) {
        int d = 32 * w + dtl * 16 + l15;
        const short* bsrc = memTb + d * 512 + s * 128;
#pragma unroll
        for (int kc = 0; kc < 4; ++kc) {
          s16x8 bf = *(const s16x8*)&bsrc[kc * 32 + l4 * 8];
          oacc[rt][dtl] = __builtin_amdgcn_mfma_f32_16x16x32_bf16(
              ap[kc], bf, oacc[rt][dtl], 0, 0, 0);
        }
      }
    }
    __syncthreads();  // (c) PV reads done; bufP free for next slice
  }

  // normalize att-out, packed store into bufP
#pragma unroll
  for (int rt = 0; rt < 4; ++rt)
#pragma unroll
    for (int e = 0; e < 4; ++e) {
      int row = rt * 16 + l4 * 4 + e;
      float inv = 1.f / redsum[row];
#pragma unroll
      for (int dtl = 0; dtl < 2; ++dtl) {
        float v = oacc[rt][dtl][e] * inv;
        float pv = __shfl_xor(v, 1);
        if (evn) {
          int d = 32 * w + dtl * 16 + l15;
          int slot = d >> 3;
          int phys = (slot & 8) | ((slot & 7) ^ (row & 7));
          *(unsigned*)&bufP[row * 128 + phys * 8 + (d & 7)] = pk2(v, pv);
        }
      }
    }
  __syncthreads();

  // final GEMM (swapped): A = W2 rows (p), B = rep rows (c) -> D[p][c], coalesced store
#pragma unroll
  for (int pi = 0; pi < 2; ++pi) {
    int t = w + 4 * pi;
    if (t < 6) {
      s16x8 af2[8];
#pragma unroll
      for (int kc = 0; kc < 8; ++kc)
        af2[kc] = *(const s16x8*)&W2b[(t * 16 + l15) * 256 + kc * 32 + l4 * 8];
#pragma unroll
      for (int ct = 0; ct < 4; ++ct) {
        f32x4 acc = (f32x4){0.f, 0.f, 0.f, 0.f};
#pragma unroll
        for (int kc = 0; kc < 8; ++kc) {
          int row = ct * 16 + l15;
          int slot = (kc & 3) * 4 + l4;
          int phys = (slot & 8) | ((slot & 7) ^ (row & 7));
          const short* bb = (kc < 4) ? bufP : bufR2;
          s16x8 bf = *(const s16x8*)&bb[row * 128 + phys * 8];
          acc = __builtin_amdgcn_mfma_f32_16x16x32_bf16(af2[kc], bf, acc, 0, 0, 0);
        }
        int c = ct * 16 + l15;
        if (c < valid) {
#pragma unroll
          for (int e = 0; e < 4; ++e) {
            int p = t * 16 + l4 * 4 + e;
            out[((size_t)b * P + p) * C + c0 + c] = acc[e] + b2[p];
          }
        }
      }
    }
  }
}

extern "C" void kernel_launch(void* const* d_in, const int* in_sizes, int n_in,
                              void* d_out, int out_size, void* d_ws, size_t ws_size,
                              hipStream_t stream) {
  const float* x   = (const float*)d_in[0];
  const float* W1  = (const float*)d_in[1];
  const float* b1  = (const float*)d_in[2];
  const float* Wp  = (const float*)d_in[3];
  const float* bpv = (const float*)d_in[4];
  const float* W2  = (const float*)d_in[5];
  const float* b2  = (const float*)d_in[6];
  const float* mem = (const float*)d_in[7];
  char* ws = (char*)d_ws;
  short* W1b   = (short*)(ws);             // 131072 B
  short* Wpb   = (short*)(ws + 131072);    // 32768 B
  short* W2b   = (short*)(ws + 163840);    // 49152 B
  short* memb  = (short*)(ws + 212992);    // 131072 B
  short* memTb = (short*)(ws + 344064);    // 131072 B
  short* R1b   = (short*)(ws + 475136);    // 14123008 B
  float* outp = (float*)d_out;

  k0_convert<<<672, 256, 0, stream>>>(W1, Wp, W2, mem, W1b, Wpb, W2b, memb, memTb);
  dim3 grid(CT, BATCH);
  k1_repre<<<grid, 256, 0, stream>>>(x, W1b, b1, R1b);
  k2_fused<<<grid, 256, 0, stream>>>(R1b, Wpb, bpv, memb, memTb, W2b, b2, outp);
}

// Round 3
// 185.204 us; speedup vs baseline: 1.0764x; 1.0764x over previous
//
#include <hip/hip_runtime.h>
#include <hip/hip_bf16.h>

typedef __attribute__((ext_vector_type(4))) float f32x4;
typedef __attribute__((ext_vector_type(8))) short s16x8;

#define DEVI __device__ __forceinline__

constexpr int S = 512, C = 862, P = 96, H = 128, BATCH = 64;
constexpr int CT = 14;  // ceil(862/64)

DEVI short f2bf(float f) {
  unsigned u = __builtin_bit_cast(unsigned, f);
  u += 0x7fffu + ((u >> 16) & 1u);
  return (short)(u >> 16);
}

DEVI unsigned pk2(float a, float b) {
  return (unsigned)(unsigned short)f2bf(a) | ((unsigned)(unsigned short)f2bf(b) << 16);
}

DEVI s16x8 mk8(const float* v) {
  s16x8 r;
#pragma unroll
  for (int i = 0; i < 8; ++i) r[i] = f2bf(v[i]);
  return r;
}

// ---------------- k0: weight conversions ----------------
__global__ __launch_bounds__(256) void k0_convert(
    const float* __restrict__ W1, const float* __restrict__ Wp,
    const float* __restrict__ W2, const float* __restrict__ mem,
    short* __restrict__ W1b, short* __restrict__ Wpb, short* __restrict__ W2b,
    short* __restrict__ memb, short* __restrict__ memTb) {
  int i = blockIdx.x * 256 + threadIdx.x;
  if (i < 65536) { W1b[i] = f2bf(W1[i]); return; }
  i -= 65536;
  if (i < 16384) { Wpb[i] = f2bf(Wp[i]); return; }
  i -= 16384;
  if (i < 24576) { W2b[i] = f2bf(W2[i]); return; }
  i -= 24576;
  if (i < 65536) {
    short v = f2bf(mem[i]);
    memb[i] = v;                              // [f][d]
    memTb[(i & 127) * 512 + (i >> 7)] = v;    // [d][f]
  }
}

// ---------------- k1: r1 = sigmoid(x^T W1^T + b1) ----------------
// grid (14, 64). Double-buffered LDS, reg-prefetch, 1 barrier per K-step.
__global__ __launch_bounds__(256, 3) void k1_repre(
    const float* __restrict__ x, const short* __restrict__ W1b,
    const float* __restrict__ b1, short* __restrict__ R1b) {
  __shared__ short xt[2][64 * 64];    // [c][s] 2x8KB
  __shared__ short w1t[2][128 * 64];  // [h][s] 2x16KB
  const int b = blockIdx.y;
  const int c0 = blockIdx.x * 64;
  const int tid = threadIdx.x;
  const int l = tid & 63, w = tid >> 6;
  const int l15 = l & 15, l4 = l >> 4;
  const int csub = (w >> 1) * 32, hsub = (w & 1) * 64;

  f32x4 acc[2][4];
#pragma unroll
  for (int ct = 0; ct < 2; ++ct)
#pragma unroll
    for (int ht = 0; ht < 4; ++ht) acc[ct][ht] = (f32x4){0.f, 0.f, 0.f, 0.f};

  const int cme = tid & 63;
  const bool cv = (c0 + cme) < C;
  const float* xsrc0 = x + (size_t)b * S * C + c0 + cme;
  const int hh = tid >> 1, half = tid & 1;

  float xv[2][8];
  s16x8 wv[4];
  // prefetch kt=0
  {
#pragma unroll
    for (int j = 0; j < 2; ++j) {
      int o = w + j * 4;
      const float* src = xsrc0 + (size_t)(o * 8) * C;
#pragma unroll
      for (int i = 0; i < 8; ++i) xv[j][i] = cv ? src[(size_t)i * C] : 0.f;
    }
    const short* wsrc = W1b + hh * 512;
#pragma unroll
    for (int q = 0; q < 4; ++q) wv[q] = *(const s16x8*)&wsrc[(half * 4 + q) * 8];
  }

  for (int kt = 0; kt < 8; ++kt) {
    const int pb = kt & 1;
    // write staged regs -> LDS buffer pb
#pragma unroll
    for (int j = 0; j < 2; ++j) {
      int o = w + j * 4;
      int phys = o ^ (cme & 7);
      *(s16x8*)&xt[pb][cme * 64 + phys * 8] = mk8(xv[j]);
    }
#pragma unroll
    for (int q = 0; q < 4; ++q) {
      int ss = half * 4 + q;
      int phys = ss ^ (hh & 7);
      *(s16x8*)&w1t[pb][hh * 64 + phys * 8] = wv[q];
    }
    __syncthreads();
    // issue next tile's global loads (consumed at next iteration's LDS write)
    if (kt < 7) {
      int kn = kt + 1;
#pragma unroll
      for (int j = 0; j < 2; ++j) {
        int o = w + j * 4;
        const float* src = xsrc0 + (size_t)(kn * 64 + o * 8) * C;
#pragma unroll
        for (int i = 0; i < 8; ++i) xv[j][i] = cv ? src[(size_t)i * C] : 0.f;
      }
      const short* wsrc = W1b + hh * 512 + kn * 64;
#pragma unroll
      for (int q = 0; q < 4; ++q) wv[q] = *(const s16x8*)&wsrc[(half * 4 + q) * 8];
    }
    // fragments + MFMA from buffer pb
    s16x8 af[2][2], bf[4][2];
#pragma unroll
    for (int ct = 0; ct < 2; ++ct)
#pragma unroll
      for (int kc = 0; kc < 2; ++kc) {
        int row = csub + ct * 16 + l15;
        int slot = kc * 4 + l4;
        af[ct][kc] = *(const s16x8*)&xt[pb][row * 64 + (slot ^ (row & 7)) * 8];
      }
#pragma unroll
    for (int ht = 0; ht < 4; ++ht)
#pragma unroll
      for (int kc = 0; kc < 2; ++kc) {
        int row = hsub + ht * 16 + l15;
        int slot = kc * 4 + l4;
        bf[ht][kc] = *(const s16x8*)&w1t[pb][row * 64 + (slot ^ (row & 7)) * 8];
      }
#pragma unroll
    for (int ct = 0; ct < 2; ++ct)
#pragma unroll
      for (int ht = 0; ht < 4; ++ht)
#pragma unroll
        for (int kc = 0; kc < 2; ++kc)
          acc[ct][ht] = __builtin_amdgcn_mfma_f32_16x16x32_bf16(
              af[ct][kc], bf[ht][kc], acc[ct][ht], 0, 0, 0);
  }
  // epilogue: + b1, sigmoid, store bf16
#pragma unroll
  for (int ct = 0; ct < 2; ++ct) {
#pragma unroll
    for (int ht = 0; ht < 4; ++ht) {
      int hcol = hsub + ht * 16 + l15;
      float bias = b1[hcol];
#pragma unroll
      for (int e = 0; e < 4; ++e) {
        int crow = csub + ct * 16 + l4 * 4 + e;
        if (c0 + crow < C) {
          float v = acc[ct][ht][e] + bias;
          float sg = 1.f / (1.f + __expf(-v));
          R1b[((size_t)b * C + c0 + crow) * 128 + hcol] = f2bf(sg);
        }
      }
    }
  }
}

// ---------------- k2: fused projector + codebook attention + predictor ----------------
// grid (14, 64). 64 rows/block, 4 waves. All B-operands read from global (L2-resident).
// LDS only for cross-wave r2 and P. Online softmax over 4 slices of 128.
// launch_bounds(256,3): cap ~170 VGPR -> no spills (the (256,4)=128 cap spilled:
// WRITE_SIZE 74MB vs 21MB output). 3 blocks/CU via VGPR; LDS 33KB would allow 4.
__global__ __launch_bounds__(256, 3) void k2_fused(
    const short* __restrict__ R1b, const short* __restrict__ Wpb,
    const float* __restrict__ bp, const short* __restrict__ memb,
    const short* __restrict__ memTb, const short* __restrict__ W2b,
    const float* __restrict__ b2, float* __restrict__ out) {
  __shared__ short bufR2[64 * 128];  // r2 bf16, swizzled      (16KB)
  __shared__ short bufP[64 * 128];   // P slice / att-out bf16 (16KB)
  __shared__ float redsc[64];
  __shared__ float redsum[64];

  const int b = blockIdx.y, c0 = blockIdx.x * 64;
  const int valid = (C - c0 < 64) ? (C - c0) : 64;
  const int tid = threadIdx.x, l = tid & 63, w = tid >> 6;
  const int l15 = l & 15, l4 = l >> 4;
  const bool evn = (l15 & 1) == 0;
  const size_t n0 = (size_t)b * C + c0;

  // ---- r2 = r1 @ Wp^T + bp : wave w owns rows [16w, 16w+16) ----
  {
    int rloc = 16 * w + l15;
    int rr = rloc < valid ? rloc : valid - 1;  // clamp: stay in-bounds, sane values
    const short* asrc = R1b + (n0 + rr) * 128;
    s16x8 af[4];
#pragma unroll
    for (int kc = 0; kc < 4; ++kc) af[kc] = *(const s16x8*)&asrc[(kc * 4 + l4) * 8];
#pragma unroll
    for (int gt = 0; gt < 8; ++gt) {
      f32x4 acc = (f32x4){0.f, 0.f, 0.f, 0.f};
#pragma unroll
      for (int kc = 0; kc < 4; ++kc) {
        s16x8 bf = *(const s16x8*)&Wpb[(gt * 16 + l15) * 128 + (kc * 4 + l4) * 8];
        acc = __builtin_amdgcn_mfma_f32_16x16x32_bf16(af[kc], bf, acc, 0, 0, 0);
      }
      int g = gt * 16 + l15;
      float bias = bp[g];
#pragma unroll
      for (int e = 0; e < 4; ++e) {
        float v = acc[e] + bias;
        float pv = __shfl_xor(v, 1);
        if (evn) {
          int row = 16 * w + l4 * 4 + e;
          int slot = g >> 3;
          int phys = (slot & 8) | ((slot & 7) ^ (row & 7));
          *(unsigned*)&bufR2[row * 128 + phys * 8 + (g & 7)] = pk2(v, pv);
        }
      }
    }
  }
  __syncthreads();

  // hoisted logits A-frags (own rows of r2)
  s16x8 ar[4];
#pragma unroll
  for (int kc = 0; kc < 4; ++kc) {
    int row = 16 * w + l15;
    int slot = kc * 4 + l4;
    int phys = (slot & 8) | ((slot & 7) ^ (row & 7));
    ar[kc] = *(const s16x8*)&bufR2[row * 128 + phys * 8];
  }

  float m_run[4], s_run[4];
#pragma unroll
  for (int e = 0; e < 4; ++e) { m_run[e] = -1e30f; s_run[e] = 0.f; }
  f32x4 oacc[4][2];
#pragma unroll
  for (int rt = 0; rt < 4; ++rt)
#pragma unroll
    for (int d = 0; d < 2; ++d) oacc[rt][d] = (f32x4){0.f, 0.f, 0.f, 0.f};

  for (int s = 0; s < 4; ++s) {
    // logits: own 16 rows x 128 f, B-frags straight from L2
    f32x4 lg[8];
#pragma unroll
    for (int ft = 0; ft < 8; ++ft) {
      lg[ft] = (f32x4){0.f, 0.f, 0.f, 0.f};
#pragma unroll
      for (int kc = 0; kc < 4; ++kc) {
        s16x8 bf = *(const s16x8*)&memb[(s * 128 + ft * 16 + l15) * 128 + (kc * 4 + l4) * 8];
        lg[ft] = __builtin_amdgcn_mfma_f32_16x16x32_bf16(ar[kc], bf, lg[ft], 0, 0, 0);
      }
    }
    // online softmax + packed P store
#pragma unroll
    for (int e = 0; e < 4; ++e) {
      float mx = lg[0][e];
#pragma unroll
      for (int ft = 1; ft < 8; ++ft) mx = fmaxf(mx, lg[ft][e]);
      mx = fmaxf(mx, __shfl_xor(mx, 1));
      mx = fmaxf(mx, __shfl_xor(mx, 2));
      mx = fmaxf(mx, __shfl_xor(mx, 4));
      mx = fmaxf(mx, __shfl_xor(mx, 8));
      float mn = fmaxf(m_run[e], mx);
      float sc = __expf(m_run[e] - mn);
      float ps = 0.f;
#pragma unroll
      for (int ft = 0; ft < 8; ++ft) {
        float p = __expf(lg[ft][e] - mn);
        lg[ft][e] = p;
        ps += p;
      }
      ps += __shfl_xor(ps, 1);
      ps += __shfl_xor(ps, 2);
      ps += __shfl_xor(ps, 4);
      ps += __shfl_xor(ps, 8);
      s_run[e] = s_run[e] * sc + ps;
      m_run[e] = mn;
      int row = 16 * w + l4 * 4 + e;
      if (l15 == 0) {
        redsc[row] = sc;
        if (s == 3) redsum[row] = s_run[e];
      }
#pragma unroll
      for (int ft = 0; ft < 8; ++ft) {
        float v = lg[ft][e];
        float pv = __shfl_xor(v, 1);
        if (evn) {
          int fc = ft * 16 + l15;
          int slot = fc >> 3;
          int phys = (slot & 8) | ((slot & 7) ^ (row & 7));
          *(unsigned*)&bufP[row * 128 + phys * 8 + (fc & 7)] = pk2(v, pv);
        }
      }
    }
    __syncthreads();  // (b) P + redsc visible
    // PV: wave w owns d-columns [32w, 32w+32); rescale then accumulate
#pragma unroll
    for (int rt = 0; rt < 4; ++rt)
#pragma unroll
      for (int e = 0; e < 4; ++e) {
        float sc = redsc[rt * 16 + l4 * 4 + e];
        oacc[rt][0][e] *= sc;
        oacc[rt][1][e] *= sc;
      }
#pragma unroll
    for (int rt = 0; rt < 4; ++rt) {
      s16x8 ap[4];
#pragma unroll
      for (int kc = 0; kc < 4; ++kc) {
        int row = rt * 16 + l15;
        int slot = kc * 4 + l4;
        int phys = (slot & 8) | ((slot & 7) ^ (row & 7));
        ap[kc] = *(const s16x8*)&bufP[row * 128 + phys * 8];
      }
#pragma unroll
      for (int dtl = 0; dtl < 2; ++dtl) {
        int d = 32 * w + dtl * 16 + l15;
        const short* bsrc = memTb + d * 512 + s * 128;
#pragma unroll
        for (int kc = 0; kc < 4; ++kc) {
          s16x8 bf = *(const s16x8*)&bsrc[kc * 32 + l4 * 8];
          oacc[rt][dtl] = __builtin_amdgcn_mfma_f32_16x16x32_bf16(
              ap[kc], bf, oacc[rt][dtl], 0, 0, 0);
        }
      }
    }
    __syncthreads();  // (c) PV reads done; bufP free for next slice
  }

  // normalize att-out, packed store into bufP
#pragma unroll
  for (int rt = 0; rt < 4; ++rt)
#pragma unroll
    for (int e = 0; e < 4; ++e) {
      int row = rt * 16 + l4 * 4 + e;
      float inv = 1.f / redsum[row];
#pragma unroll
      for (int dtl = 0; dtl < 2; ++dtl) {
        float v = oacc[rt][dtl][e] * inv;
        float pv = __shfl_xor(v, 1);
        if (evn) {
          int d = 32 * w + dtl * 16 + l15;
          int slot = d >> 3;
          int phys = (slot & 8) | ((slot & 7) ^ (row & 7));
          *(unsigned*)&bufP[row * 128 + phys * 8 + (d & 7)] = pk2(v, pv);
        }
      }
    }
  __syncthreads();

  // final GEMM (swapped): A = W2 rows (p), B = rep rows (c) -> D[p][c], coalesced store
#pragma unroll
  for (int pi = 0; pi < 2; ++pi) {
    int t = w + 4 * pi;
    if (t < 6) {
      s16x8 af2[8];
#pragma unroll
      for (int kc = 0; kc < 8; ++kc)
        af2[kc] = *(const s16x8*)&W2b[(t * 16 + l15) * 256 + kc * 32 + l4 * 8];
#pragma unroll
      for (int ct = 0; ct < 4; ++ct) {
        f32x4 acc = (f32x4){0.f, 0.f, 0.f, 0.f};
#pragma unroll
        for (int kc = 0; kc < 8; ++kc) {
          int row = ct * 16 + l15;
          int slot = (kc & 3) * 4 + l4;
          int phys = (slot & 8) | ((slot & 7) ^ (row & 7));
          const short* bb = (kc < 4) ? bufP : bufR2;
          s16x8 bf = *(const s16x8*)&bb[row * 128 + phys * 8];
          acc = __builtin_amdgcn_mfma_f32_16x16x32_bf16(af2[kc], bf, acc, 0, 0, 0);
        }
        int c = ct * 16 + l15;
        if (c < valid) {
#pragma unroll
          for (int e = 0; e < 4; ++e) {
            int p = t * 16 + l4 * 4 + e;
            out[((size_t)b * P + p) * C + c0 + c] = acc[e] + b2[p];
          }
        }
      }
    }
  }
}

extern "C" void kernel_launch(void* const* d_in, const int* in_sizes, int n_in,
                              void* d_out, int out_size, void* d_ws, size_t ws_size,
                              hipStream_t stream) {
  const float* x   = (const float*)d_in[0];
  const float* W1  = (const float*)d_in[1];
  const float* b1  = (const float*)d_in[2];
  const float* Wp  = (const float*)d_in[3];
  const float* bpv = (const float*)d_in[4];
  const float* W2  = (const float*)d_in[5];
  const float* b2  = (const float*)d_in[6];
  const float* mem = (const float*)d_in[7];
  char* ws = (char*)d_ws;
  short* W1b   = (short*)(ws);             // 131072 B
  short* Wpb   = (short*)(ws + 131072);    // 32768 B
  short* W2b   = (short*)(ws + 163840);    // 49152 B
  short* memb  = (short*)(ws + 212992);    // 131072 B
  short* memTb = (short*)(ws + 344064);    // 131072 B
  short* R1b   = (short*)(ws + 475136);    // 14123008 B
  float* outp = (float*)d_out;

  k0_convert<<<672, 256, 0, stream>>>(W1, Wp, W2, mem, W1b, Wpb, W2b, memb, memTb);
  dim3 grid(CT, BATCH);
  k1_repre<<<grid, 256, 0, stream>>>(x, W1b, b1, R1b);
  k2_fused<<<grid, 256, 0, stream>>>(R1b, Wpb, bpv, memb, memTb, W2b, b2, outp);
}